// Round 2
// baseline (1957.634 us; speedup 1.0000x reference)
//
#include <hip/hip_runtime.h>
#include <hip/hip_cooperative_groups.h>

namespace cg = cooperative_groups;

#define NN 10000
#define CC 16
#define CAP 96     // max nnz/row; E[nnz]=33, sigma~5.7 -> ~11 sigma headroom
#define CAPP 97    // padded LDS stride: 97*8B => bank offset 2 per row-group, kills 4-way conflict
#define RPB 16     // rows per block (RPB*CC == 256 threads)
#define NBLK 625   // NN / RPB

// ---- train_mask storage-format-agnostic accessor -------------------------
// mode 0: int32 0/1, mode 1: uint8 bool, mode 2: float32 0.0/1.0
__device__ __forceinline__ bool mask_at(const void* p, int i, int mode) {
    if (mode == 0) return ((const int*)p)[i] != 0;
    if (mode == 1) return ((const unsigned char*)p)[i] != 0;
    return ((const float*)p)[i] != 0.0f;
}

// ===========================================================================
// Fused persistent kernel: mode-detect + CSR-in-LDS + 10 SpMV steps +
// Gumbel ST hardening + masked SpMV + row-normalize + MSE, one dispatch.
// Block b owns rows [b*16, b*16+16); thread t: row = b*16 + (t>>4), c = t&15.
// ===========================================================================
__global__ __launch_bounds__(256, 3) void fused_lp(
        const float* __restrict__ adj,
        const float* __restrict__ labels,
        const float* __restrict__ pseudo,
        const float* __restrict__ gumbel,
        const void*  __restrict__ tmask,
        float* __restrict__ Ya,
        float* __restrict__ Yb,
        float* __restrict__ partial,
        float* __restrict__ out)
{
    cg::grid_group grid = cg::this_grid();

    __shared__ int2 s_pack[RPB][CAPP];   // e.x = col*CC (pre-scaled), e.y = bits(val)
    __shared__ int  s_cnt[RPB];
    __shared__ int  s_ib, s_fb, s_mode;
    __shared__ float sw[4];

    const int b    = blockIdx.x;
    const int tid  = threadIdx.x;
    const int row0 = b * RPB;
    const int lr   = tid >> 4;           // local row 0..15
    const int c    = tid & 15;
    const int row  = row0 + lr;
    const int t    = b * 256 + tid;      // == row*CC + c

    // ---- phase 0a: mask storage-mode detect (redundant per block, ~10KB) --
    if (tid == 0) { s_ib = 0; s_fb = 0; }
    if (tid < RPB) s_cnt[tid] = 0;
    __syncthreads();
    {
        const unsigned int* mw = (const unsigned int*)tmask;
        int ib = 0, fb = 0;
        for (int i = tid; i < NN / 4; i += 256) {
            unsigned w = mw[i];
            ib |= (w > 1u);
            fb |= (w != 0u && w != 0x3F800000u);
        }
        if (ib) s_ib = 1;                 // benign racy same-value store
        if (fb) s_fb = 1;
    }

    // ---- phase 0b: CSR build straight into LDS (16 rows, 640KB stream) ----
    for (int idx = tid; idx < RPB * (NN / 4); idx += 256) {
        int r = idx / (NN / 4);
        int i = idx - r * (NN / 4);
        float4 v = ((const float4*)(adj + (size_t)(row0 + r) * NN))[i];
        int j = i * 4;
        if (v.x != 0.f) { int p = atomicAdd(&s_cnt[r], 1); if (p < CAP) s_pack[r][p] = make_int2((j    ) * CC, __float_as_int(v.x)); }
        if (v.y != 0.f) { int p = atomicAdd(&s_cnt[r], 1); if (p < CAP) s_pack[r][p] = make_int2((j + 1) * CC, __float_as_int(v.y)); }
        if (v.z != 0.f) { int p = atomicAdd(&s_cnt[r], 1); if (p < CAP) s_pack[r][p] = make_int2((j + 2) * CC, __float_as_int(v.z)); }
        if (v.w != 0.f) { int p = atomicAdd(&s_cnt[r], 1); if (p < CAP) s_pack[r][p] = make_int2((j + 3) * CC, __float_as_int(v.w)); }
    }
    if (tid == 0) s_mode = s_ib ? (s_fb ? 1 : 2) : 0;
    __syncthreads();
    if (tid < RPB && s_cnt[tid] > CAP) s_cnt[tid] = CAP;
    __syncthreads();

    const int  mode = s_mode;
    const int  n    = s_cnt[lr];
    const bool m    = mask_at(tmask, row, mode);
    const float lbl = labels[t];         // loaded once, reused across all 10 steps

    // ---- step 1: Y1 = m ? labels : adj @ (mask ? labels : 0) -------------
    {
        float acc = 0.f;
        #pragma unroll 4
        for (int k = 0; k < n; ++k) {
            int2 e = s_pack[lr][k];
            float yv = mask_at(tmask, e.x >> 4, mode) ? labels[e.x + c] : 0.f;
            acc = fmaf(__int_as_float(e.y), yv, acc);
        }
        Ya[t] = m ? lbl : acc;
    }
    __threadfence();
    grid.sync();

    // ---- steps 2..9 ------------------------------------------------------
    float* cur = Ya;
    float* nxt = Yb;
    for (int it = 0; it < 8; ++it) {
        float acc = 0.f;
        #pragma unroll 4
        for (int k = 0; k < n; ++k) {
            int2 e = s_pack[lr][k];
            acc = fmaf(__int_as_float(e.y), cur[e.x + c], acc);
        }
        nxt[t] = m ? lbl : acc;
        __threadfence();
        grid.sync();
        float* tmp = cur; cur = nxt; nxt = tmp;
    }

    // ---- step 10 + Gumbel straight-through hardening (16-lane row group) -
    {
        float acc = 0.f;
        #pragma unroll 4
        for (int k = 0; k < n; ++k) {
            int2 e = s_pack[lr][k];
            acc = fmaf(__int_as_float(e.y), cur[e.x + c], acc);
        }
        float y10 = m ? lbl : acc;
        float l = y10 + gumbel[t];                 // TAU = 1
        float mx = l;
        for (int off = 8; off >= 1; off >>= 1) mx = fmaxf(mx, __shfl_xor(mx, off, 16));
        float e_ = expf(l - mx);
        float s = e_;
        for (int off = 8; off >= 1; off >>= 1) s += __shfl_xor(s, off, 16);
        float soft = e_ / s;
        float hard = (l == mx) ? 1.0f : 0.0f;
        float y = (hard + soft) - soft;            // faithful ST forward
        nxt[t] = m ? lbl : y;
    }
    __threadfence();
    grid.sync();
    const float* Y2 = nxt;

    // ---- dist = (adj!=0)@Y2, row-normalize, MSE per-block partial --------
    {
        float acc = 0.f;
        #pragma unroll 4
        for (int k = 0; k < n; ++k) acc += Y2[s_pack[lr][k].x + c];
        float rs = acc;                            // row sum (diag guarantees rs>0)
        for (int off = 8; off >= 1; off >>= 1) rs += __shfl_xor(rs, off, 16);
        float d = acc / rs - pseudo[t];
        float contrib = d * d * (1.0f / (NN * CC));
        for (int off = 32; off >= 1; off >>= 1) contrib += __shfl_down(contrib, off, 64);
        if ((tid & 63) == 0) sw[tid >> 6] = contrib;
        __syncthreads();
        if (tid == 0) partial[b] = sw[0] + sw[1] + sw[2] + sw[3];
    }
    __threadfence();
    grid.sync();

    // ---- final reduce on block 0 -----------------------------------------
    if (b == 0) {
        float s = 0.f;
        for (int i = tid; i < NBLK; i += 256) s += partial[i];
        for (int off = 32; off >= 1; off >>= 1) s += __shfl_down(s, off, 64);
        if ((tid & 63) == 0) sw[tid >> 6] = s;
        __syncthreads();
        if (tid == 0) out[0] = sw[0] + sw[1] + sw[2] + sw[3];
    }
}

// ===========================================================================
// Fallback chain (previous verified 13-dispatch version) — used only if
// cooperative launch is rejected by the runtime/capture.
// ===========================================================================
__global__ __launch_bounds__(256) void build_csr(const float* __restrict__ adj,
                                                 int2* __restrict__ pack,
                                                 int* __restrict__ cnt,
                                                 const unsigned int* __restrict__ mask_words,
                                                 int* __restrict__ flag) {
    if (blockIdx.x == NN) {
        __shared__ int s_int_bad, s_flt_bad;
        if (threadIdx.x == 0) { s_int_bad = 0; s_flt_bad = 0; }
        __syncthreads();
        for (int i = threadIdx.x; i < NN / 4; i += 256) {
            unsigned w = mask_words[i];
            if (w > 1u) s_int_bad = 1;
            if (w != 0u && w != 0x3F800000u) s_flt_bad = 1;
        }
        __syncthreads();
        if (threadIdx.x == 0) {
            int mode;
            if (!s_int_bad)      mode = 0;
            else if (!s_flt_bad) mode = 2;
            else                 mode = 1;
            *flag = mode;
        }
        return;
    }
    __shared__ int lcnt;
    const int row = blockIdx.x;
    if (threadIdx.x == 0) lcnt = 0;
    __syncthreads();
    const float4* rp = (const float4*)(adj + (size_t)row * NN);
    int2* pb = pack + row * CAP;
    for (int i = threadIdx.x; i < NN / 4; i += 256) {
        float4 v = rp[i];
        int j = i * 4;
        if (v.x != 0.f) { int p = atomicAdd(&lcnt, 1); if (p < CAP) pb[p] = make_int2(j,     __float_as_int(v.x)); }
        if (v.y != 0.f) { int p = atomicAdd(&lcnt, 1); if (p < CAP) pb[p] = make_int2(j + 1, __float_as_int(v.y)); }
        if (v.z != 0.f) { int p = atomicAdd(&lcnt, 1); if (p < CAP) pb[p] = make_int2(j + 2, __float_as_int(v.z)); }
        if (v.w != 0.f) { int p = atomicAdd(&lcnt, 1); if (p < CAP) pb[p] = make_int2(j + 3, __float_as_int(v.w)); }
    }
    __syncthreads();
    if (threadIdx.x == 0) cnt[row] = (lcnt < CAP) ? lcnt : CAP;
}

__global__ __launch_bounds__(256) void spmv_first(const int2* __restrict__ pack,
                                                  const int* __restrict__ cnt,
                                                  const float* __restrict__ labels,
                                                  const void* __restrict__ tmask,
                                                  const int* __restrict__ flag,
                                                  float* __restrict__ Yout) {
    int t = blockIdx.x * 256 + threadIdx.x;
    int row = t >> 4, c = t & 15;
    int n = cnt[row];
    int mode = *flag;
    const int2* pp = pack + row * CAP;
    float acc = 0.0f;
    #pragma unroll 4
    for (int k = 0; k < n; k++) {
        int2 e = pp[k];
        float yv = mask_at(tmask, e.x, mode) ? labels[e.x * CC + c] : 0.0f;
        acc = fmaf(__int_as_float(e.y), yv, acc);
    }
    bool m = mask_at(tmask, row, mode);
    Yout[t] = m ? labels[t] : acc;
}

__global__ __launch_bounds__(256) void spmv_step(const int2* __restrict__ pack,
                                                 const int* __restrict__ cnt,
                                                 const float* __restrict__ Yin,
                                                 const float* __restrict__ labels,
                                                 const void* __restrict__ tmask,
                                                 const int* __restrict__ flag,
                                                 float* __restrict__ Yout) {
    int t = blockIdx.x * 256 + threadIdx.x;
    int row = t >> 4, c = t & 15;
    int n = cnt[row];
    const int2* pp = pack + row * CAP;
    float acc = 0.0f;
    #pragma unroll 4
    for (int k = 0; k < n; k++) {
        int2 e = pp[k];
        acc = fmaf(__int_as_float(e.y), Yin[e.x * CC + c], acc);
    }
    bool m = mask_at(tmask, row, *flag);
    Yout[t] = m ? labels[t] : acc;
}

__global__ __launch_bounds__(256) void spmv_harden(const int2* __restrict__ pack,
                                                   const int* __restrict__ cnt,
                                                   const float* __restrict__ Yin,
                                                   const float* __restrict__ labels,
                                                   const float* __restrict__ gumbel,
                                                   const void* __restrict__ tmask,
                                                   const int* __restrict__ flag,
                                                   float* __restrict__ Yout) {
    int t = blockIdx.x * 256 + threadIdx.x;
    int row = t >> 4, c = t & 15;
    int n = cnt[row];
    const int2* pp = pack + row * CAP;
    float acc = 0.0f;
    #pragma unroll 4
    for (int k = 0; k < n; k++) {
        int2 e = pp[k];
        acc = fmaf(__int_as_float(e.y), Yin[e.x * CC + c], acc);
    }
    bool m = mask_at(tmask, row, *flag);
    float lbl = labels[t];
    float y10 = m ? lbl : acc;
    float l = y10 + gumbel[t];
    float mx = l;
    for (int off = 8; off >= 1; off >>= 1) mx = fmaxf(mx, __shfl_xor(mx, off, 16));
    float e = expf(l - mx);
    float s = e;
    for (int off = 8; off >= 1; off >>= 1) s += __shfl_xor(s, off, 16);
    float soft = e / s;
    float hard = (l == mx) ? 1.0f : 0.0f;
    float y = (hard + soft) - soft;
    Yout[t] = m ? lbl : y;
}

__global__ __launch_bounds__(256) void mask_spmv_loss(const int2* __restrict__ pack,
                                                      const int* __restrict__ cnt,
                                                      const float* __restrict__ Y2,
                                                      const float* __restrict__ pseudo,
                                                      float* __restrict__ partial) {
    int t = blockIdx.x * 256 + threadIdx.x;
    int row = t >> 4, c = t & 15;
    int n = cnt[row];
    const int2* pp = pack + row * CAP;
    float acc = 0.0f;
    #pragma unroll 4
    for (int k = 0; k < n; k++) acc += Y2[pp[k].x * CC + c];
    float rs = acc;
    for (int off = 8; off >= 1; off >>= 1) rs += __shfl_xor(rs, off, 16);
    float d = acc / rs - pseudo[t];
    float contrib = d * d * (1.0f / (NN * CC));
    for (int off = 32; off >= 1; off >>= 1) contrib += __shfl_down(contrib, off, 64);
    __shared__ float sw[4];
    if ((threadIdx.x & 63) == 0) sw[threadIdx.x >> 6] = contrib;
    __syncthreads();
    if (threadIdx.x == 0) partial[blockIdx.x] = sw[0] + sw[1] + sw[2] + sw[3];
}

__global__ void final_reduce(const float* __restrict__ partial, float* __restrict__ out) {
    float s = 0.0f;
    for (int i = threadIdx.x; i < NBLK; i += 256) s += partial[i];
    for (int off = 32; off >= 1; off >>= 1) s += __shfl_down(s, off, 64);
    __shared__ float sw[4];
    if ((threadIdx.x & 63) == 0) sw[threadIdx.x >> 6] = s;
    __syncthreads();
    if (threadIdx.x == 0) out[0] = sw[0] + sw[1] + sw[2] + sw[3];
}

extern "C" void kernel_launch(void* const* d_in, const int* in_sizes, int n_in,
                              void* d_out, int out_size, void* d_ws, size_t ws_size,
                              hipStream_t stream) {
    const float* adj    = (const float*)d_in[0];
    const float* labels = (const float*)d_in[1];
    const float* pseudo = (const float*)d_in[2];
    const float* gumbel = (const float*)d_in[3];
    const void*  tmask  = d_in[4];
    // d_in[5] = iter_step (10), d_in[6] = k_hop (1): fixed scalars in setup.

    char* ws = (char*)d_ws;                          // same layout as verified baseline
    int*   flag    = (int*)(ws + 0);                 // 64 B reserved
    int*   cnt     = (int*)(ws + 64);                // 40,000 B
    int2*  pack    = (int2*)(ws + 40064);            // 7,680,000 B (fallback only)
    float* Ya      = (float*)(ws + 7720064);         // 640,000 B
    float* Yb      = (float*)(ws + 8360064);         // 640,000 B
    float* partial = (float*)(ws + 9000064);         // 2,500 B

    float* outp = (float*)d_out;

    void* args[] = { (void*)&adj, (void*)&labels, (void*)&pseudo, (void*)&gumbel,
                     (void*)&tmask, (void*)&Ya, (void*)&Yb, (void*)&partial, (void*)&outp };
    hipError_t err = hipLaunchCooperativeKernel((void*)fused_lp, dim3(NBLK), dim3(256),
                                                args, 0, stream);
    if (err == hipSuccess) return;
    (void)hipGetLastError();                         // clear sticky error, run fallback

    build_csr<<<NN + 1, 256, 0, stream>>>(adj, pack, cnt, (const unsigned int*)tmask, flag);
    spmv_first<<<NBLK, 256, 0, stream>>>(pack, cnt, labels, tmask, flag, Ya);
    float* cur = Ya;
    float* nxt = Yb;
    for (int it = 0; it < 8; ++it) {
        spmv_step<<<NBLK, 256, 0, stream>>>(pack, cnt, cur, labels, tmask, flag, nxt);
        float* tmp = cur; cur = nxt; nxt = tmp;
    }
    spmv_harden<<<NBLK, 256, 0, stream>>>(pack, cnt, cur, labels, gumbel, tmask, flag, nxt);
    mask_spmv_loss<<<NBLK, 256, 0, stream>>>(pack, cnt, nxt, pseudo, partial);
    final_reduce<<<1, 256, 0, stream>>>(partial, outp);
}

// Round 3
// 1111.325 us; speedup vs baseline: 1.7615x; 1.7615x over previous
//
#include <hip/hip_runtime.h>

#define NN 10000
#define CC 16
#define CAP 96     // max nnz/row; E[nnz]=33, sigma~5.7 -> ~11 sigma headroom
#define CAPP 97    // padded LDS stride
#define RPB 16     // rows per block (RPB*CC == 256 threads)
#define NBLK 625   // NN / RPB
#define AGT __HIP_MEMORY_SCOPE_AGENT

// ---- coherent (sc1, L2-bypassing) scalar access helpers ------------------
// Cross-XCD-visible without any cache-wide fences: relaxed agent-scope
// atomics route through the coherence point (Infinity Cache).
static __device__ __forceinline__ float ld_coh(const float* p) {
    return __hip_atomic_load((float*)p, __ATOMIC_RELAXED, AGT);
}
static __device__ __forceinline__ void st_coh(float* p, float v) {
    __hip_atomic_store(p, v, __ATOMIC_RELAXED, AGT);
}

// ---- monotone spin barrier: one fresh counter per barrier, no reset ------
// Arrival: release fetch_add (drains vmcnt -> prior sc1 stores are globally
// visible; any compiler-emitted wbl2 is cheap since Y stores don't dirty L2).
// Wait: relaxed spin + s_sleep; one acquire load on exit for formality.
static __device__ __forceinline__ void gbar(int* slot) {
    __syncthreads();
    if (threadIdx.x == 0) {
        __hip_atomic_fetch_add(slot, 1, __ATOMIC_RELEASE, AGT);
        while (__hip_atomic_load(slot, __ATOMIC_RELAXED, AGT) != NBLK)
            __builtin_amdgcn_s_sleep(16);
        (void)__hip_atomic_load(slot, __ATOMIC_ACQUIRE, AGT);
    }
    __syncthreads();
}

// ---- train_mask storage-format-agnostic accessor -------------------------
// mode 0: int32 0/1, mode 1: uint8 bool, mode 2: float32 0.0/1.0
__device__ __forceinline__ bool mask_at(const void* p, int i, int mode) {
    if (mode == 0) return ((const int*)p)[i] != 0;
    if (mode == 1) return ((const unsigned char*)p)[i] != 0;
    return ((const float*)p)[i] != 0.0f;
}

// ===========================================================================
// Fused persistent kernel, fence-free sync design.
// Block b owns rows [b*16, b*16+16); thread t: row = b*16 + (t>>4), c = t&15.
// bars[0..9]  = barrier counters (memset to 0 pre-launch)
// bars[15]    = last-arriver counter for the final reduction
// ===========================================================================
__global__ __launch_bounds__(256, 3) void fused_lp(
        const float* __restrict__ adj,
        const float* __restrict__ labels,
        const float* __restrict__ pseudo,
        const float* __restrict__ gumbel,
        const void*  __restrict__ tmask,
        float* __restrict__ Ya,
        float* __restrict__ Yb,
        float* __restrict__ partial,
        float* __restrict__ out,
        int*   __restrict__ bars)
{
    __shared__ int2 s_pack[RPB][CAPP];   // e.x = col*CC (pre-scaled), e.y = bits(val)
    __shared__ int  s_cnt[RPB];
    __shared__ int  s_ib, s_fb, s_mode, s_last;
    __shared__ float sw[4];

    const int b    = blockIdx.x;
    const int tid  = threadIdx.x;
    const int row0 = b * RPB;
    const int lr   = tid >> 4;           // local row 0..15
    const int c    = tid & 15;
    const int row  = row0 + lr;
    const int t    = b * 256 + tid;      // == row*CC + c

    // ---- phase 0a: mask storage-mode detect (block-local, ~10KB read) ----
    if (tid == 0) { s_ib = 0; s_fb = 0; }
    if (tid < RPB) s_cnt[tid] = 0;
    __syncthreads();
    {
        const unsigned int* mw = (const unsigned int*)tmask;
        int ib = 0, fb = 0;
        for (int i = tid; i < NN / 4; i += 256) {
            unsigned w = mw[i];
            ib |= (w > 1u);
            fb |= (w != 0u && w != 0x3F800000u);
        }
        if (ib) s_ib = 1;                 // benign racy same-value store
        if (fb) s_fb = 1;
    }

    // ---- phase 0b: CSR build into LDS, 2-deep load prefetch --------------
    {
        const int TOT = RPB * (NN / 4);   // 40000
        int idx = tid;
        int r0_ = idx / (NN / 4), i0_ = idx - r0_ * (NN / 4);
        float4 v = ((const float4*)(adj + (size_t)(row0 + r0_) * NN))[i0_];
        while (idx < TOT) {
            int nidx = idx + 256;
            float4 nv = v;
            if (nidx < TOT) {             // issue next load before processing current
                int rn = nidx / (NN / 4), in_ = nidx - rn * (NN / 4);
                nv = ((const float4*)(adj + (size_t)(row0 + rn) * NN))[in_];
            }
            int r = idx / (NN / 4);
            int j = (idx - r * (NN / 4)) * 4;
            if (v.x != 0.f) { int p = atomicAdd(&s_cnt[r], 1); if (p < CAP) s_pack[r][p] = make_int2((j    ) * CC, __float_as_int(v.x)); }
            if (v.y != 0.f) { int p = atomicAdd(&s_cnt[r], 1); if (p < CAP) s_pack[r][p] = make_int2((j + 1) * CC, __float_as_int(v.y)); }
            if (v.z != 0.f) { int p = atomicAdd(&s_cnt[r], 1); if (p < CAP) s_pack[r][p] = make_int2((j + 2) * CC, __float_as_int(v.z)); }
            if (v.w != 0.f) { int p = atomicAdd(&s_cnt[r], 1); if (p < CAP) s_pack[r][p] = make_int2((j + 3) * CC, __float_as_int(v.w)); }
            idx = nidx; v = nv;
        }
    }
    if (tid == 0) s_mode = s_ib ? (s_fb ? 1 : 2) : 0;
    __syncthreads();
    if (tid < RPB && s_cnt[tid] > CAP) s_cnt[tid] = CAP;
    __syncthreads();

    const int  mode = s_mode;
    const int  n    = s_cnt[lr];
    const bool m    = mask_at(tmask, row, mode);
    const float lbl = labels[t];         // loaded once, reused across all 10 steps

    // ---- step 1: Y1 = m ? labels : adj @ (mask ? labels : 0) -------------
    {
        float acc = 0.f;
        #pragma unroll 4
        for (int k = 0; k < n; ++k) {
            int2 e = s_pack[lr][k];
            float yv = mask_at(tmask, e.x >> 4, mode) ? labels[e.x + c] : 0.f;
            acc = fmaf(__int_as_float(e.y), yv, acc);
        }
        st_coh(&Ya[t], m ? lbl : acc);
    }
    gbar(bars + 0);

    // ---- steps 2..9 ------------------------------------------------------
    float* cur = Ya;
    float* nxt = Yb;
    for (int it = 0; it < 8; ++it) {
        float acc = 0.f;
        #pragma unroll 4
        for (int k = 0; k < n; ++k) {
            int2 e = s_pack[lr][k];
            acc = fmaf(__int_as_float(e.y), ld_coh(&cur[e.x + c]), acc);
        }
        st_coh(&nxt[t], m ? lbl : acc);
        gbar(bars + 1 + it);
        float* tmp = cur; cur = nxt; nxt = tmp;
    }

    // ---- step 10 + Gumbel straight-through hardening (16-lane row group) -
    {
        float acc = 0.f;
        #pragma unroll 4
        for (int k = 0; k < n; ++k) {
            int2 e = s_pack[lr][k];
            acc = fmaf(__int_as_float(e.y), ld_coh(&cur[e.x + c]), acc);
        }
        float y10 = m ? lbl : acc;
        float l = y10 + gumbel[t];                 // TAU = 1
        float mx = l;
        for (int off = 8; off >= 1; off >>= 1) mx = fmaxf(mx, __shfl_xor(mx, off, 16));
        float e_ = expf(l - mx);
        float s = e_;
        for (int off = 8; off >= 1; off >>= 1) s += __shfl_xor(s, off, 16);
        float soft = e_ / s;
        float hard = (l == mx) ? 1.0f : 0.0f;
        float y = (hard + soft) - soft;            // faithful ST forward
        st_coh(&nxt[t], m ? lbl : y);
    }
    gbar(bars + 9);
    const float* Y2 = nxt;

    // ---- dist = (adj!=0)@Y2, row-normalize, MSE per-block partial --------
    {
        float acc = 0.f;
        #pragma unroll 4
        for (int k = 0; k < n; ++k) acc += ld_coh(&Y2[s_pack[lr][k].x + c]);
        float rs = acc;                            // row sum (diag guarantees rs>0)
        for (int off = 8; off >= 1; off >>= 1) rs += __shfl_xor(rs, off, 16);
        float d = acc / rs - pseudo[t];
        float contrib = d * d * (1.0f / (NN * CC));
        for (int off = 32; off >= 1; off >>= 1) contrib += __shfl_down(contrib, off, 64);
        if ((tid & 63) == 0) sw[tid >> 6] = contrib;
        __syncthreads();
        if (tid == 0) {
            st_coh(&partial[b], sw[0] + sw[1] + sw[2] + sw[3]);
            int old = __hip_atomic_fetch_add(bars + 15, 1, __ATOMIC_ACQ_REL, AGT);
            s_last = (old == NBLK - 1);            // last arriver finishes the job
        }
        __syncthreads();
    }

    // ---- final reduce, done by the last-arriving block (no 11th barrier) -
    if (s_last) {
        float s = 0.f;
        for (int i = tid; i < NBLK; i += 256) s += ld_coh(&partial[i]);
        for (int off = 32; off >= 1; off >>= 1) s += __shfl_down(s, off, 64);
        if ((tid & 63) == 0) sw[tid >> 6] = s;
        __syncthreads();
        if (tid == 0) out[0] = sw[0] + sw[1] + sw[2] + sw[3];
    }
}

// ===========================================================================
// Fallback chain (verified 629us 13-dispatch version) — used only if
// cooperative launch is rejected by the runtime/capture.
// ===========================================================================
__global__ __launch_bounds__(256) void build_csr(const float* __restrict__ adj,
                                                 int2* __restrict__ pack,
                                                 int* __restrict__ cnt,
                                                 const unsigned int* __restrict__ mask_words,
                                                 int* __restrict__ flag) {
    if (blockIdx.x == NN) {
        __shared__ int s_int_bad, s_flt_bad;
        if (threadIdx.x == 0) { s_int_bad = 0; s_flt_bad = 0; }
        __syncthreads();
        for (int i = threadIdx.x; i < NN / 4; i += 256) {
            unsigned w = mask_words[i];
            if (w > 1u) s_int_bad = 1;
            if (w != 0u && w != 0x3F800000u) s_flt_bad = 1;
        }
        __syncthreads();
        if (threadIdx.x == 0) {
            int mode;
            if (!s_int_bad)      mode = 0;
            else if (!s_flt_bad) mode = 2;
            else                 mode = 1;
            *flag = mode;
        }
        return;
    }
    __shared__ int lcnt;
    const int row = blockIdx.x;
    if (threadIdx.x == 0) lcnt = 0;
    __syncthreads();
    const float4* rp = (const float4*)(adj + (size_t)row * NN);
    int2* pb = pack + row * CAP;
    for (int i = threadIdx.x; i < NN / 4; i += 256) {
        float4 v = rp[i];
        int j = i * 4;
        if (v.x != 0.f) { int p = atomicAdd(&lcnt, 1); if (p < CAP) pb[p] = make_int2(j,     __float_as_int(v.x)); }
        if (v.y != 0.f) { int p = atomicAdd(&lcnt, 1); if (p < CAP) pb[p] = make_int2(j + 1, __float_as_int(v.y)); }
        if (v.z != 0.f) { int p = atomicAdd(&lcnt, 1); if (p < CAP) pb[p] = make_int2(j + 2, __float_as_int(v.z)); }
        if (v.w != 0.f) { int p = atomicAdd(&lcnt, 1); if (p < CAP) pb[p] = make_int2(j + 3, __float_as_int(v.w)); }
    }
    __syncthreads();
    if (threadIdx.x == 0) cnt[row] = (lcnt < CAP) ? lcnt : CAP;
}

__global__ __launch_bounds__(256) void spmv_first(const int2* __restrict__ pack,
                                                  const int* __restrict__ cnt,
                                                  const float* __restrict__ labels,
                                                  const void* __restrict__ tmask,
                                                  const int* __restrict__ flag,
                                                  float* __restrict__ Yout) {
    int t = blockIdx.x * 256 + threadIdx.x;
    int row = t >> 4, c = t & 15;
    int n = cnt[row];
    int mode = *flag;
    const int2* pp = pack + row * CAP;
    float acc = 0.0f;
    #pragma unroll 4
    for (int k = 0; k < n; k++) {
        int2 e = pp[k];
        float yv = mask_at(tmask, e.x, mode) ? labels[e.x * CC + c] : 0.0f;
        acc = fmaf(__int_as_float(e.y), yv, acc);
    }
    bool m = mask_at(tmask, row, mode);
    Yout[t] = m ? labels[t] : acc;
}

__global__ __launch_bounds__(256) void spmv_step(const int2* __restrict__ pack,
                                                 const int* __restrict__ cnt,
                                                 const float* __restrict__ Yin,
                                                 const float* __restrict__ labels,
                                                 const void* __restrict__ tmask,
                                                 const int* __restrict__ flag,
                                                 float* __restrict__ Yout) {
    int t = blockIdx.x * 256 + threadIdx.x;
    int row = t >> 4, c = t & 15;
    int n = cnt[row];
    const int2* pp = pack + row * CAP;
    float acc = 0.0f;
    #pragma unroll 4
    for (int k = 0; k < n; k++) {
        int2 e = pp[k];
        acc = fmaf(__int_as_float(e.y), Yin[e.x * CC + c], acc);
    }
    bool m = mask_at(tmask, row, *flag);
    Yout[t] = m ? labels[t] : acc;
}

__global__ __launch_bounds__(256) void spmv_harden(const int2* __restrict__ pack,
                                                   const int* __restrict__ cnt,
                                                   const float* __restrict__ Yin,
                                                   const float* __restrict__ labels,
                                                   const float* __restrict__ gumbel,
                                                   const void* __restrict__ tmask,
                                                   const int* __restrict__ flag,
                                                   float* __restrict__ Yout) {
    int t = blockIdx.x * 256 + threadIdx.x;
    int row = t >> 4, c = t & 15;
    int n = cnt[row];
    const int2* pp = pack + row * CAP;
    float acc = 0.0f;
    #pragma unroll 4
    for (int k = 0; k < n; k++) {
        int2 e = pp[k];
        acc = fmaf(__int_as_float(e.y), Yin[e.x * CC + c], acc);
    }
    bool m = mask_at(tmask, row, *flag);
    float lbl = labels[t];
    float y10 = m ? lbl : acc;
    float l = y10 + gumbel[t];
    float mx = l;
    for (int off = 8; off >= 1; off >>= 1) mx = fmaxf(mx, __shfl_xor(mx, off, 16));
    float e = expf(l - mx);
    float s = e;
    for (int off = 8; off >= 1; off >>= 1) s += __shfl_xor(s, off, 16);
    float soft = e / s;
    float hard = (l == mx) ? 1.0f : 0.0f;
    float y = (hard + soft) - soft;
    Yout[t] = m ? lbl : y;
}

__global__ __launch_bounds__(256) void mask_spmv_loss(const int2* __restrict__ pack,
                                                      const int* __restrict__ cnt,
                                                      const float* __restrict__ Y2,
                                                      const float* __restrict__ pseudo,
                                                      float* __restrict__ partial) {
    int t = blockIdx.x * 256 + threadIdx.x;
    int row = t >> 4, c = t & 15;
    int n = cnt[row];
    const int2* pp = pack + row * CAP;
    float acc = 0.0f;
    #pragma unroll 4
    for (int k = 0; k < n; k++) acc += Y2[pp[k].x * CC + c];
    float rs = acc;
    for (int off = 8; off >= 1; off >>= 1) rs += __shfl_xor(rs, off, 16);
    float d = acc / rs - pseudo[t];
    float contrib = d * d * (1.0f / (NN * CC));
    for (int off = 32; off >= 1; off >>= 1) contrib += __shfl_down(contrib, off, 64);
    __shared__ float sw[4];
    if ((threadIdx.x & 63) == 0) sw[threadIdx.x >> 6] = contrib;
    __syncthreads();
    if (threadIdx.x == 0) partial[blockIdx.x] = sw[0] + sw[1] + sw[2] + sw[3];
}

__global__ void final_reduce(const float* __restrict__ partial, float* __restrict__ out) {
    float s = 0.0f;
    for (int i = threadIdx.x; i < NBLK; i += 256) s += partial[i];
    for (int off = 32; off >= 1; off >>= 1) s += __shfl_down(s, off, 64);
    __shared__ float sw[4];
    if ((threadIdx.x & 63) == 0) sw[threadIdx.x >> 6] = s;
    __syncthreads();
    if (threadIdx.x == 0) out[0] = sw[0] + sw[1] + sw[2] + sw[3];
}

extern "C" void kernel_launch(void* const* d_in, const int* in_sizes, int n_in,
                              void* d_out, int out_size, void* d_ws, size_t ws_size,
                              hipStream_t stream) {
    const float* adj    = (const float*)d_in[0];
    const float* labels = (const float*)d_in[1];
    const float* pseudo = (const float*)d_in[2];
    const float* gumbel = (const float*)d_in[3];
    const void*  tmask  = d_in[4];
    // d_in[5] = iter_step (10), d_in[6] = k_hop (1): fixed scalars in setup.

    char* ws = (char*)d_ws;
    int*   flag    = (int*)(ws + 0);                 // 64 B reserved (fallback)
    int*   cnt     = (int*)(ws + 64);                // 40,000 B (fallback)
    int2*  pack    = (int2*)(ws + 40064);            // 7,680,000 B (fallback only)
    float* Ya      = (float*)(ws + 7720064);         // 640,000 B
    float* Yb      = (float*)(ws + 8360064);         // 640,000 B
    float* partial = (float*)(ws + 9000064);         // 2,500 B (end 9,002,564)
    int*   bars    = (int*)(ws + 9002624);           // 128 B barrier state

    float* outp = (float*)d_out;

    // zero barrier state (stream-ordered, graph-capture-safe tiny memset)
    hipMemsetAsync(bars, 0, 128, stream);

    void* args[] = { (void*)&adj, (void*)&labels, (void*)&pseudo, (void*)&gumbel,
                     (void*)&tmask, (void*)&Ya, (void*)&Yb, (void*)&partial,
                     (void*)&outp, (void*)&bars };
    hipError_t err = hipLaunchCooperativeKernel((void*)fused_lp, dim3(NBLK), dim3(256),
                                                args, 0, stream);
    if (err == hipSuccess) return;
    (void)hipGetLastError();                         // clear sticky error, run fallback

    build_csr<<<NN + 1, 256, 0, stream>>>(adj, pack, cnt, (const unsigned int*)tmask, flag);
    spmv_first<<<NBLK, 256, 0, stream>>>(pack, cnt, labels, tmask, flag, Ya);
    float* cur = Ya;
    float* nxt = Yb;
    for (int it = 0; it < 8; ++it) {
        spmv_step<<<NBLK, 256, 0, stream>>>(pack, cnt, cur, labels, tmask, flag, nxt);
        float* tmp = cur; cur = nxt; nxt = tmp;
    }
    spmv_harden<<<NBLK, 256, 0, stream>>>(pack, cnt, cur, labels, gumbel, tmask, flag, nxt);
    mask_spmv_loss<<<NBLK, 256, 0, stream>>>(pack, cnt, nxt, pseudo, partial);
    final_reduce<<<1, 256, 0, stream>>>(partial, outp);
}

// Round 4
// 843.641 us; speedup vs baseline: 2.3205x; 1.3173x over previous
//
#include <hip/hip_runtime.h>

#define NN 10000
#define CC 16
#define CAP 96     // max nnz/row; E[nnz]=33, sigma~5.7 -> ~11 sigma headroom; divisible by 8
#define CAPP 97    // padded LDS stride
#define RPB 16     // rows per block (RPB*CC == 256 threads)
#define NBLK 625   // NN / RPB
#define AGT __HIP_MEMORY_SCOPE_AGENT

// ---- coherent (sc1, L3-point-of-coherence) scalar access helpers ---------
// Relaxed agent-scope atomics: no cache-maintenance ops, coherent at the
// Infinity Cache. Visibility across XCDs needs only vmcnt completion.
static __device__ __forceinline__ float ld_coh(const float* p) {
    return __hip_atomic_load((float*)p, __ATOMIC_RELAXED, AGT);
}
static __device__ __forceinline__ void st_coh(float* p, float v) {
    __hip_atomic_store(p, v, __ATOMIC_RELAXED, AGT);
}

// ---- pure-relaxed spin barrier: NO release (no buffer_wbl2), NO acquire --
// (no buffer_inv). Prior sc1 stores are globally visible once vmcnt drains;
// the explicit asm drain before the relaxed RMW provides exactly that.
static __device__ __forceinline__ void gbar(int* slot) {
    __syncthreads();
    if (threadIdx.x == 0) {
        asm volatile("s_waitcnt vmcnt(0)" ::: "memory");
        __hip_atomic_fetch_add(slot, 1, __ATOMIC_RELAXED, AGT);
        while (__hip_atomic_load(slot, __ATOMIC_RELAXED, AGT) != NBLK)
            __builtin_amdgcn_s_sleep(16);
    }
    __syncthreads();
}

// ---- train_mask storage-format-agnostic accessor -------------------------
// mode 0: int32 0/1, mode 1: uint8 bool, mode 2: float32 0.0/1.0
__device__ __forceinline__ bool mask_at(const void* p, int i, int mode) {
    if (mode == 0) return ((const int*)p)[i] != 0;
    if (mode == 1) return ((const unsigned char*)p)[i] != 0;
    return ((const float*)p)[i] != 0.0f;
}

// Batched SpMV accumulate over a padded (multiple-of-8) CSR row held in LDS.
// 8 independent sc1 loads are issued before any use -> 8-deep MLP instead of
// serialized ~900-cycle L3 round trips (atomics aren't compiler-pipelined).
// Padded entries have weight 0.0 and col 0 -> contribute exactly 0.
static __device__ __forceinline__ float spmv_row8(const int2* __restrict__ prow,
                                                  int n8, int c,
                                                  const float* __restrict__ cur) {
    float acc = 0.f;
    for (int k = 0; k < n8; k += 8) {
        int2 e[8];
        #pragma unroll
        for (int i = 0; i < 8; ++i) e[i] = prow[k + i];
        float y[8];
        #pragma unroll
        for (int i = 0; i < 8; ++i) y[i] = ld_coh(&cur[e[i].x + c]);
        #pragma unroll
        for (int i = 0; i < 8; ++i) acc = fmaf(__int_as_float(e[i].y), y[i], acc);
    }
    return acc;
}

// ===========================================================================
// Fused persistent kernel, zero-cache-op sync design.
// Block b owns rows [b*16, b*16+16); thread t: row = b*16 + (t>>4), c = t&15.
// bars[0..9] = barrier counters (memset to 0 pre-launch); bars[15] = arriver.
// ===========================================================================
__global__ __launch_bounds__(256, 3) void fused_lp(
        const float* __restrict__ adj,
        const float* __restrict__ labels,
        const float* __restrict__ pseudo,
        const float* __restrict__ gumbel,
        const void*  __restrict__ tmask,
        float* __restrict__ Ya,
        float* __restrict__ Yb,
        float* __restrict__ partial,
        float* __restrict__ out,
        int*   __restrict__ bars)
{
    __shared__ int2 s_pack[RPB][CAPP];   // e.x = col*CC (pre-scaled), e.y = bits(val)
    __shared__ int  s_cnt[RPB];
    __shared__ int  s_ib, s_fb, s_mode, s_last;
    __shared__ float sw[4];

    const int b    = blockIdx.x;
    const int tid  = threadIdx.x;
    const int row0 = b * RPB;
    const int lr   = tid >> 4;           // local row 0..15
    const int c    = tid & 15;
    const int row  = row0 + lr;
    const int t    = b * 256 + tid;      // == row*CC + c

    // ---- phase 0a: mask storage-mode detect (block-local, ~10KB read) ----
    if (tid == 0) { s_ib = 0; s_fb = 0; }
    if (tid < RPB) s_cnt[tid] = 0;
    __syncthreads();
    {
        const unsigned int* mw = (const unsigned int*)tmask;
        int ib = 0, fb = 0;
        for (int i = tid; i < NN / 4; i += 256) {
            unsigned w = mw[i];
            ib |= (w > 1u);
            fb |= (w != 0u && w != 0x3F800000u);
        }
        if (ib) s_ib = 1;                 // benign racy same-value store
        if (fb) s_fb = 1;
    }

    // ---- phase 0b: CSR build into LDS, 2-deep load prefetch --------------
    {
        const int TOT = RPB * (NN / 4);   // 40000
        int idx = tid;
        int r0_ = idx / (NN / 4), i0_ = idx - r0_ * (NN / 4);
        float4 v = ((const float4*)(adj + (size_t)(row0 + r0_) * NN))[i0_];
        while (idx < TOT) {
            int nidx = idx + 256;
            float4 nv = v;
            if (nidx < TOT) {             // issue next load before processing current
                int rn = nidx / (NN / 4), in_ = nidx - rn * (NN / 4);
                nv = ((const float4*)(adj + (size_t)(row0 + rn) * NN))[in_];
            }
            int r = idx / (NN / 4);
            int j = (idx - r * (NN / 4)) * 4;
            if (v.x != 0.f) { int p = atomicAdd(&s_cnt[r], 1); if (p < CAP) s_pack[r][p] = make_int2((j    ) * CC, __float_as_int(v.x)); }
            if (v.y != 0.f) { int p = atomicAdd(&s_cnt[r], 1); if (p < CAP) s_pack[r][p] = make_int2((j + 1) * CC, __float_as_int(v.y)); }
            if (v.z != 0.f) { int p = atomicAdd(&s_cnt[r], 1); if (p < CAP) s_pack[r][p] = make_int2((j + 2) * CC, __float_as_int(v.z)); }
            if (v.w != 0.f) { int p = atomicAdd(&s_cnt[r], 1); if (p < CAP) s_pack[r][p] = make_int2((j + 3) * CC, __float_as_int(v.w)); }
            idx = nidx; v = nv;
        }
    }
    if (tid == 0) s_mode = s_ib ? (s_fb ? 1 : 2) : 0;
    __syncthreads();
    // clamp + zero-weight pad each row to a multiple of 8 (batched loop)
    if (tid < RPB) {
        int nr = s_cnt[tid] < CAP ? s_cnt[tid] : CAP;
        s_cnt[tid] = nr;
        int n8 = (nr + 7) & ~7;           // <= CAP (96 % 8 == 0)
        for (int k = nr; k < n8; ++k) s_pack[tid][k] = make_int2(0, 0);
    }
    __syncthreads();

    const int  mode = s_mode;
    const int  n    = s_cnt[lr];
    const int  n8   = (n + 7) & ~7;
    const bool m    = mask_at(tmask, row, mode);
    const float lbl = labels[t];         // loaded once, reused across all 10 steps

    // ---- step 1: Y1 = m ? labels : adj @ (mask ? labels : 0) -------------
    // (plain loads: labels is read-only input, no coherence concern)
    {
        float acc = 0.f;
        #pragma unroll 4
        for (int k = 0; k < n; ++k) {
            int2 e = s_pack[lr][k];
            float yv = mask_at(tmask, e.x >> 4, mode) ? labels[e.x + c] : 0.f;
            acc = fmaf(__int_as_float(e.y), yv, acc);
        }
        st_coh(&Ya[t], m ? lbl : acc);
    }
    gbar(bars + 0);

    // ---- steps 2..9 ------------------------------------------------------
    float* cur = Ya;
    float* nxt = Yb;
    for (int it = 0; it < 8; ++it) {
        float acc = spmv_row8(&s_pack[lr][0], n8, c, cur);
        st_coh(&nxt[t], m ? lbl : acc);
        gbar(bars + 1 + it);
        float* tmp = cur; cur = nxt; nxt = tmp;
    }

    // ---- step 10 + Gumbel straight-through hardening (16-lane row group) -
    {
        float acc = spmv_row8(&s_pack[lr][0], n8, c, cur);
        float y10 = m ? lbl : acc;
        float l = y10 + gumbel[t];                 // TAU = 1
        float mx = l;
        for (int off = 8; off >= 1; off >>= 1) mx = fmaxf(mx, __shfl_xor(mx, off, 16));
        float e_ = expf(l - mx);
        float s = e_;
        for (int off = 8; off >= 1; off >>= 1) s += __shfl_xor(s, off, 16);
        float soft = e_ / s;
        float hard = (l == mx) ? 1.0f : 0.0f;
        float y = (hard + soft) - soft;            // faithful ST forward
        st_coh(&nxt[t], m ? lbl : y);
    }
    gbar(bars + 9);
    const float* Y2 = nxt;

    // ---- dist = (adj!=0)@Y2, row-normalize, MSE per-block partial --------
    {
        float acc = 0.f;
        for (int k = 0; k < n8; k += 8) {          // batched; pad guarded by e.y==0
            int2 e[8];
            #pragma unroll
            for (int i = 0; i < 8; ++i) e[i] = s_pack[lr][k + i];
            float y[8];
            #pragma unroll
            for (int i = 0; i < 8; ++i) y[i] = ld_coh(&Y2[e[i].x + c]);
            #pragma unroll
            for (int i = 0; i < 8; ++i) acc += (e[i].y != 0) ? y[i] : 0.f;
        }
        float rs = acc;                            // row sum (diag guarantees rs>0)
        for (int off = 8; off >= 1; off >>= 1) rs += __shfl_xor(rs, off, 16);
        float d = acc / rs - pseudo[t];
        float contrib = d * d * (1.0f / (NN * CC));
        for (int off = 32; off >= 1; off >>= 1) contrib += __shfl_down(contrib, off, 64);
        if ((tid & 63) == 0) sw[tid >> 6] = contrib;
        __syncthreads();
        if (tid == 0) {
            st_coh(&partial[b], sw[0] + sw[1] + sw[2] + sw[3]);
            asm volatile("s_waitcnt vmcnt(0)" ::: "memory");   // partial visible at L3
            int old = __hip_atomic_fetch_add(bars + 15, 1, __ATOMIC_RELAXED, AGT);
            s_last = (old == NBLK - 1);            // last arriver finishes the job
        }
        __syncthreads();
    }

    // ---- final reduce, done by the last-arriving block (no 11th barrier) -
    if (s_last) {
        float s = 0.f;
        for (int i = tid; i < NBLK; i += 256) s += ld_coh(&partial[i]);
        for (int off = 32; off >= 1; off >>= 1) s += __shfl_down(s, off, 64);
        if ((tid & 63) == 0) sw[tid >> 6] = s;
        __syncthreads();
        if (tid == 0) out[0] = sw[0] + sw[1] + sw[2] + sw[3];
    }
}

// ===========================================================================
// Fallback chain (verified 629us 13-dispatch version) — used only if
// cooperative launch is rejected by the runtime/capture.
// ===========================================================================
__global__ __launch_bounds__(256) void build_csr(const float* __restrict__ adj,
                                                 int2* __restrict__ pack,
                                                 int* __restrict__ cnt,
                                                 const unsigned int* __restrict__ mask_words,
                                                 int* __restrict__ flag) {
    if (blockIdx.x == NN) {
        __shared__ int s_int_bad, s_flt_bad;
        if (threadIdx.x == 0) { s_int_bad = 0; s_flt_bad = 0; }
        __syncthreads();
        for (int i = threadIdx.x; i < NN / 4; i += 256) {
            unsigned w = mask_words[i];
            if (w > 1u) s_int_bad = 1;
            if (w != 0u && w != 0x3F800000u) s_flt_bad = 1;
        }
        __syncthreads();
        if (threadIdx.x == 0) {
            int mode;
            if (!s_int_bad)      mode = 0;
            else if (!s_flt_bad) mode = 2;
            else                 mode = 1;
            *flag = mode;
        }
        return;
    }
    __shared__ int lcnt;
    const int row = blockIdx.x;
    if (threadIdx.x == 0) lcnt = 0;
    __syncthreads();
    const float4* rp = (const float4*)(adj + (size_t)row * NN);
    int2* pb = pack + row * CAP;
    for (int i = threadIdx.x; i < NN / 4; i += 256) {
        float4 v = rp[i];
        int j = i * 4;
        if (v.x != 0.f) { int p = atomicAdd(&lcnt, 1); if (p < CAP) pb[p] = make_int2(j,     __float_as_int(v.x)); }
        if (v.y != 0.f) { int p = atomicAdd(&lcnt, 1); if (p < CAP) pb[p] = make_int2(j + 1, __float_as_int(v.y)); }
        if (v.z != 0.f) { int p = atomicAdd(&lcnt, 1); if (p < CAP) pb[p] = make_int2(j + 2, __float_as_int(v.z)); }
        if (v.w != 0.f) { int p = atomicAdd(&lcnt, 1); if (p < CAP) pb[p] = make_int2(j + 3, __float_as_int(v.w)); }
    }
    __syncthreads();
    if (threadIdx.x == 0) cnt[row] = (lcnt < CAP) ? lcnt : CAP;
}

__global__ __launch_bounds__(256) void spmv_first(const int2* __restrict__ pack,
                                                  const int* __restrict__ cnt,
                                                  const float* __restrict__ labels,
                                                  const void* __restrict__ tmask,
                                                  const int* __restrict__ flag,
                                                  float* __restrict__ Yout) {
    int t = blockIdx.x * 256 + threadIdx.x;
    int row = t >> 4, c = t & 15;
    int n = cnt[row];
    int mode = *flag;
    const int2* pp = pack + row * CAP;
    float acc = 0.0f;
    #pragma unroll 4
    for (int k = 0; k < n; k++) {
        int2 e = pp[k];
        float yv = mask_at(tmask, e.x, mode) ? labels[e.x * CC + c] : 0.0f;
        acc = fmaf(__int_as_float(e.y), yv, acc);
    }
    bool m = mask_at(tmask, row, mode);
    Yout[t] = m ? labels[t] : acc;
}

__global__ __launch_bounds__(256) void spmv_step(const int2* __restrict__ pack,
                                                 const int* __restrict__ cnt,
                                                 const float* __restrict__ Yin,
                                                 const float* __restrict__ labels,
                                                 const void* __restrict__ tmask,
                                                 const int* __restrict__ flag,
                                                 float* __restrict__ Yout) {
    int t = blockIdx.x * 256 + threadIdx.x;
    int row = t >> 4, c = t & 15;
    int n = cnt[row];
    const int2* pp = pack + row * CAP;
    float acc = 0.0f;
    #pragma unroll 4
    for (int k = 0; k < n; k++) {
        int2 e = pp[k];
        acc = fmaf(__int_as_float(e.y), Yin[e.x * CC + c], acc);
    }
    bool m = mask_at(tmask, row, *flag);
    Yout[t] = m ? labels[t] : acc;
}

__global__ __launch_bounds__(256) void spmv_harden(const int2* __restrict__ pack,
                                                   const int* __restrict__ cnt,
                                                   const float* __restrict__ Yin,
                                                   const float* __restrict__ labels,
                                                   const float* __restrict__ gumbel,
                                                   const void* __restrict__ tmask,
                                                   const int* __restrict__ flag,
                                                   float* __restrict__ Yout) {
    int t = blockIdx.x * 256 + threadIdx.x;
    int row = t >> 4, c = t & 15;
    int n = cnt[row];
    const int2* pp = pack + row * CAP;
    float acc = 0.0f;
    #pragma unroll 4
    for (int k = 0; k < n; k++) {
        int2 e = pp[k];
        acc = fmaf(__int_as_float(e.y), Yin[e.x * CC + c], acc);
    }
    bool m = mask_at(tmask, row, *flag);
    float lbl = labels[t];
    float y10 = m ? lbl : acc;
    float l = y10 + gumbel[t];
    float mx = l;
    for (int off = 8; off >= 1; off >>= 1) mx = fmaxf(mx, __shfl_xor(mx, off, 16));
    float e = expf(l - mx);
    float s = e;
    for (int off = 8; off >= 1; off >>= 1) s += __shfl_xor(s, off, 16);
    float soft = e / s;
    float hard = (l == mx) ? 1.0f : 0.0f;
    float y = (hard + soft) - soft;
    Yout[t] = m ? lbl : y;
}

__global__ __launch_bounds__(256) void mask_spmv_loss(const int2* __restrict__ pack,
                                                      const int* __restrict__ cnt,
                                                      const float* __restrict__ Y2,
                                                      const float* __restrict__ pseudo,
                                                      float* __restrict__ partial) {
    int t = blockIdx.x * 256 + threadIdx.x;
    int row = t >> 4, c = t & 15;
    int n = cnt[row];
    const int2* pp = pack + row * CAP;
    float acc = 0.0f;
    #pragma unroll 4
    for (int k = 0; k < n; k++) acc += Y2[pp[k].x * CC + c];
    float rs = acc;
    for (int off = 8; off >= 1; off >>= 1) rs += __shfl_xor(rs, off, 16);
    float d = acc / rs - pseudo[t];
    float contrib = d * d * (1.0f / (NN * CC));
    for (int off = 32; off >= 1; off >>= 1) contrib += __shfl_down(contrib, off, 64);
    __shared__ float sw[4];
    if ((threadIdx.x & 63) == 0) sw[threadIdx.x >> 6] = contrib;
    __syncthreads();
    if (threadIdx.x == 0) partial[blockIdx.x] = sw[0] + sw[1] + sw[2] + sw[3];
}

__global__ void final_reduce(const float* __restrict__ partial, float* __restrict__ out) {
    float s = 0.0f;
    for (int i = threadIdx.x; i < NBLK; i += 256) s += partial[i];
    for (int off = 32; off >= 1; off >>= 1) s += __shfl_down(s, off, 64);
    __shared__ float sw[4];
    if ((threadIdx.x & 63) == 0) sw[threadIdx.x >> 6] = s;
    __syncthreads();
    if (threadIdx.x == 0) out[0] = sw[0] + sw[1] + sw[2] + sw[3];
}

extern "C" void kernel_launch(void* const* d_in, const int* in_sizes, int n_in,
                              void* d_out, int out_size, void* d_ws, size_t ws_size,
                              hipStream_t stream) {
    const float* adj    = (const float*)d_in[0];
    const float* labels = (const float*)d_in[1];
    const float* pseudo = (const float*)d_in[2];
    const float* gumbel = (const float*)d_in[3];
    const void*  tmask  = d_in[4];
    // d_in[5] = iter_step (10), d_in[6] = k_hop (1): fixed scalars in setup.

    char* ws = (char*)d_ws;
    int*   flag    = (int*)(ws + 0);                 // 64 B reserved (fallback)
    int*   cnt     = (int*)(ws + 64);                // 40,000 B (fallback)
    int2*  pack    = (int2*)(ws + 40064);            // 7,680,000 B (fallback only)
    float* Ya      = (float*)(ws + 7720064);         // 640,000 B
    float* Yb      = (float*)(ws + 8360064);         // 640,000 B
    float* partial = (float*)(ws + 9000064);         // 2,500 B (end 9,002,564)
    int*   bars    = (int*)(ws + 9002624);           // 128 B barrier state

    float* outp = (float*)d_out;

    // zero barrier state (stream-ordered, graph-capture-safe tiny memset)
    hipMemsetAsync(bars, 0, 128, stream);

    void* args[] = { (void*)&adj, (void*)&labels, (void*)&pseudo, (void*)&gumbel,
                     (void*)&tmask, (void*)&Ya, (void*)&Yb, (void*)&partial,
                     (void*)&outp, (void*)&bars };
    hipError_t err = hipLaunchCooperativeKernel((void*)fused_lp, dim3(NBLK), dim3(256),
                                                args, 0, stream);
    if (err == hipSuccess) return;
    (void)hipGetLastError();                         // clear sticky error, run fallback

    build_csr<<<NN + 1, 256, 0, stream>>>(adj, pack, cnt, (const unsigned int*)tmask, flag);
    spmv_first<<<NBLK, 256, 0, stream>>>(pack, cnt, labels, tmask, flag, Ya);
    float* cur = Ya;
    float* nxt = Yb;
    for (int it = 0; it < 8; ++it) {
        spmv_step<<<NBLK, 256, 0, stream>>>(pack, cnt, cur, labels, tmask, flag, nxt);
        float* tmp = cur; cur = nxt; nxt = tmp;
    }
    spmv_harden<<<NBLK, 256, 0, stream>>>(pack, cnt, cur, labels, gumbel, tmask, flag, nxt);
    mask_spmv_loss<<<NBLK, 256, 0, stream>>>(pack, cnt, nxt, pseudo, partial);
    final_reduce<<<1, 256, 0, stream>>>(partial, outp);
}